// Round 1
// baseline (877.828 us; speedup 1.0000x reference)
//
#include <hip/hip_runtime.h>
#include <math.h>

#define B_    64
#define I_    512
#define C_    32
#define PRED_ 96
#define PL_   16
#define ST_   8
#define NH_   8
#define PN_   64
#define N_    2048

__device__ __forceinline__ float geluf(float x) {
    return 0.5f * x * (1.0f + erff(x * 0.70710678118654752f));
}
__device__ __forceinline__ float softplusf(float x) {
    return fmaxf(x, 0.0f) + log1pf(__expf(-fabsf(x)));
}

// ---------------------------------------------------------------- k_head
// smean = mean_l s[b,l,c]; h = gelu(smean@rw1^T+rb1); p = softmax(h@rw2^T+rb2)
__global__ void k_head(const float* __restrict__ s, const float* __restrict__ rw1,
                       const float* __restrict__ rb1, const float* __restrict__ rw2,
                       const float* __restrict__ rb2, float* __restrict__ wp) {
    int b = blockIdx.x, t = threadIdx.x;  // 256 threads
    __shared__ float part[8][32];
    __shared__ float smean[32];
    __shared__ float h[16];
    int c = t & 31, chunk = t >> 5;
    float acc = 0.f;
    for (int l = chunk * 64; l < chunk * 64 + 64; ++l)
        acc += s[((size_t)b * I_ + l) * C_ + c];
    part[chunk][c] = acc;
    __syncthreads();
    if (t < 32) {
        float v = 0.f;
#pragma unroll
        for (int i = 0; i < 8; ++i) v += part[i][t];
        smean[t] = v * (1.0f / I_);
    }
    __syncthreads();
    if (t < 16) {
        float a = rb1[t];
#pragma unroll
        for (int c2 = 0; c2 < 32; ++c2) a += smean[c2] * rw1[t * 32 + c2];
        h[t] = geluf(a);
    }
    __syncthreads();
    if (t == 0) {
        float lg[3], mx = -1e30f;
        for (int k = 0; k < 3; ++k) {
            float a = rb2[k];
            for (int j = 0; j < 16; ++j) a += h[j] * rw2[k * 16 + j];
            lg[k] = a; mx = fmaxf(mx, a);
        }
        float d = 0.f;
        for (int k = 0; k < 3; ++k) { lg[k] = __expf(lg[k] - mx); d += lg[k]; }
        float inv = 1.f / d;
        for (int k = 0; k < 3; ++k) wp[b * 3 + k] = lg[k] * inv;
    }
}

// ---------------------------------------------------------------- k_phi
// phi_mean[b,l] = sum_k p[b,k] * mean_c Pk[(cyc+l)%Wk, c];  then patch-window mean
__global__ void k_phi(const float* __restrict__ P0, const float* __restrict__ P1,
                      const float* __restrict__ P2, const int* __restrict__ cyc,
                      const float* __restrict__ wp, float* __restrict__ phis) {
    int b = blockIdx.x, t = threadIdx.x;  // 128 threads
    __shared__ float pm[I_];
    float p0 = wp[b * 3 + 0], p1 = wp[b * 3 + 1], p2 = wp[b * 3 + 2];
    int cy = cyc[b];
    for (int l = t; l < I_; l += 128) {
        float acc = 0.f;
        {
            int idx = (cy + l) % 24;
            const float4* r = (const float4*)(P0 + idx * 32);
            float s4 = 0.f;
#pragma unroll
            for (int i = 0; i < 8; ++i) { float4 v = r[i]; s4 += v.x + v.y + v.z + v.w; }
            acc += p0 * s4;
        }
        {
            int idx = (cy + l) % 168;
            const float4* r = (const float4*)(P1 + idx * 32);
            float s4 = 0.f;
#pragma unroll
            for (int i = 0; i < 8; ++i) { float4 v = r[i]; s4 += v.x + v.y + v.z + v.w; }
            acc += p1 * s4;
        }
        {
            int idx = (cy + l) % 336;
            const float4* r = (const float4*)(P2 + idx * 32);
            float s4 = 0.f;
#pragma unroll
            for (int i = 0; i < 8; ++i) { float4 v = r[i]; s4 += v.x + v.y + v.z + v.w; }
            acc += p2 * s4;
        }
        pm[l] = acc * (1.0f / 32.0f);
    }
    __syncthreads();
    if (t < PN_) {
        float sum = 0.f;
#pragma unroll
        for (int j = 0; j < 16; ++j) {
            int l = t * ST_ + j; if (l > 511) l = 511;
            sum += pm[l];
        }
        phis[b * PN_ + t] = sum * (1.0f / 16.0f);
    }
}

// ---------------------------------------------------------------- k_attn (heavy)
// For (b,scale): Qr row per thread; S = Qr . s / sqrt(C); online softmax; cs = Aw @ s.
// Writes p[b,k]-scaled cs to ws.
__global__ void __launch_bounds__(128) k_attn(
        const float* __restrict__ s, const int* __restrict__ cyc,
        const float* __restrict__ A0, const float* __restrict__ A1, const float* __restrict__ A2,
        const float* __restrict__ P0, const float* __restrict__ P1, const float* __restrict__ P2,
        const float* __restrict__ wp, float* __restrict__ wcs) {
    int l = blockIdx.x * 128 + threadIdx.x;  // row
    int k3 = blockIdx.y, b = blockIdx.z;
    const float* Atab; const float* Ptab; int Wk;
    if (k3 == 0)      { Atab = A0; Ptab = P0; Wk = 24;  }
    else if (k3 == 1) { Atab = A1; Ptab = P1; Wk = 168; }
    else              { Atab = A2; Ptab = P2; Wk = 336; }
    int idx = (cyc[b] + l) % Wk;
    float4 qr[8];
    {
        const float4* Ar = (const float4*)(Atab + idx * 32);
        const float4* Pr = (const float4*)(Ptab + idx * 32);
#pragma unroll
        for (int i = 0; i < 8; ++i) {
            float4 a = Ar[i], p = Pr[i];
            float4 q;
            q.x = softplusf(a.x) * cosf(p.x);
            q.y = softplusf(a.y) * cosf(p.y);
            q.z = softplusf(a.z) * cosf(p.z);
            q.w = softplusf(a.w) * cosf(p.w);
            qr[i] = q;
        }
    }
    const float4* sb = (const float4*)(s + (size_t)b * I_ * C_);
    const float rs = 0.17677669529663687f;  // 1/sqrt(32)
    float m = -1e30f, d = 0.f;
#pragma unroll 2
    for (int kk = 0; kk < I_; ++kk) {
        const float4* srow = sb + kk * 8;
        float acc = 0.f;
#pragma unroll
        for (int i = 0; i < 8; ++i) {
            float4 v = srow[i];
            acc += qr[i].x * v.x + qr[i].y * v.y + qr[i].z * v.z + qr[i].w * v.w;
        }
        float S = acc * rs;
        float nm = fmaxf(m, S);
        d = d * __expf(m - nm) + __expf(S - nm);
        m = nm;
    }
    float wnorm = wp[b * 3 + k3] / d;
    float4 cs[8];
#pragma unroll
    for (int i = 0; i < 8; ++i) cs[i] = make_float4(0.f, 0.f, 0.f, 0.f);
#pragma unroll 2
    for (int kk = 0; kk < I_; ++kk) {
        const float4* srow = sb + kk * 8;
        float4 sv[8];
        float acc = 0.f;
#pragma unroll
        for (int i = 0; i < 8; ++i) {
            sv[i] = srow[i];
            acc += qr[i].x * sv[i].x + qr[i].y * sv[i].y + qr[i].z * sv[i].z + qr[i].w * sv[i].w;
        }
        float w = __expf(acc * rs - m) * wnorm;
#pragma unroll
        for (int i = 0; i < 8; ++i) {
            cs[i].x += w * sv[i].x; cs[i].y += w * sv[i].y;
            cs[i].z += w * sv[i].z; cs[i].w += w * sv[i].w;
        }
    }
    float* outp = wcs + ((size_t)(k3 * B_ + b) * C_) * I_ + l;
#pragma unroll
    for (int i = 0; i < 8; ++i) {
        outp[(size_t)(i * 4 + 0) * I_] = cs[i].x;
        outp[(size_t)(i * 4 + 1) * I_] = cs[i].y;
        outp[(size_t)(i * 4 + 2) * I_] = cs[i].z;
        outp[(size_t)(i * 4 + 3) * I_] = cs[i].w;
    }
}

// ---------------------------------------------------------------- k_combine
// s_row[n,l] = s[b,l,c] + sum_k cs_k ;  t_row[n,l] = t[b,l,c]
__global__ void k_combine(const float* __restrict__ s, const float* __restrict__ t,
                          const float* __restrict__ wcs, float* __restrict__ srow,
                          float* __restrict__ trow) {
    size_t e = (size_t)blockIdx.x * 256 + threadIdx.x;  // < N_*I_
    int n = (int)(e >> 9), l = (int)(e & 511);
    int b = n >> 5, c = n & 31;
    const size_t CH = (size_t)B_ * C_ * I_;
    float v = s[((size_t)b * I_ + l) * C_ + c];
    v += wcs[e] + wcs[CH + e] + wcs[2 * CH + e];
    srow[e] = v;
    trow[e] = t[((size_t)b * I_ + l) * C_ + c];
}

// ---------------------------------------------------------------- k_patch
// per-row patch attention (PL=16, 64 patches, 8 heads of dim 2) + Wo + gelu(sp+o)
__global__ void __launch_bounds__(64) k_patch(
        const float* __restrict__ srow, const float* __restrict__ phis,
        const float* __restrict__ Wqkv, const float* __restrict__ bqkv,
        const float* __restrict__ Wo, const float* __restrict__ bo,
        const float* __restrict__ alpha_p, float* __restrict__ sx) {
    int n = blockIdx.x, t = threadIdx.x;  // 64 threads, t = patch index
    int b = n >> 5;
    __shared__ float klds[64][16];
    __shared__ float vlds[64][16];
    __shared__ float blds[64][65];
    __shared__ float phil[64];
    float alpha = alpha_p[0];
    float sp[16];
    const float* srn = srow + (size_t)n * I_;
#pragma unroll
    for (int j = 0; j < 16; ++j) {
        int l = t * ST_ + j; if (l > 511) l = 511;
        sp[j] = srn[l];
    }
    phil[t] = phis[b * PN_ + t];
    __syncthreads();
    float phit = phil[t];
    for (int ss = 0; ss < 64; ++ss) blds[t][ss] = alpha * cosf(phit - phil[ss]);
    float q[16];
#pragma unroll
    for (int o = 0; o < 16; ++o) {
        float a = bqkv[o], ka = bqkv[16 + o], va = bqkv[32 + o];
#pragma unroll
        for (int i2 = 0; i2 < 16; ++i2) {
            float spv = sp[i2];
            a  += spv * Wqkv[o * 16 + i2];
            ka += spv * Wqkv[(16 + o) * 16 + i2];
            va += spv * Wqkv[(32 + o) * 16 + i2];
        }
        q[o] = a; klds[t][o] = ka; vlds[t][o] = va;
    }
    __syncthreads();
    const float rs2 = 0.70710678118654752f;  // 1/sqrt(2)
    float o2in[16];
#pragma unroll
    for (int h = 0; h < 8; ++h) {
        float q0 = q[2 * h], q1 = q[2 * h + 1];
        float mh = -1e30f;
        for (int ss = 0; ss < 64; ++ss) {
            float sc = (q0 * klds[ss][2 * h] + q1 * klds[ss][2 * h + 1]) * rs2 + blds[t][ss];
            mh = fmaxf(mh, sc);
        }
        float dh = 0.f, o0 = 0.f, o1 = 0.f;
        for (int ss = 0; ss < 64; ++ss) {
            float sc = (q0 * klds[ss][2 * h] + q1 * klds[ss][2 * h + 1]) * rs2 + blds[t][ss];
            float w = __expf(sc - mh);
            dh += w; o0 += w * vlds[ss][2 * h]; o1 += w * vlds[ss][2 * h + 1];
        }
        float inv = 1.f / dh;
        o2in[2 * h] = o0 * inv; o2in[2 * h + 1] = o1 * inv;
    }
    float* sxr = sx + ((size_t)n * PN_ + t) * PL_;
#pragma unroll
    for (int i2 = 0; i2 < 16; ++i2) {
        float a = bo[i2];
#pragma unroll
        for (int j = 0; j < 16; ++j) a += o2in[j] * Wo[i2 * 16 + j];
        sxr[i2] = geluf(sp[i2] + a);
    }
}

// ---------------------------------------------------------------- k_bn
// batchnorm over (n, j) per patch index pn, in place
__global__ void k_bn(float* __restrict__ sx, const float* __restrict__ g,
                     const float* __restrict__ bb) {
    int pn = blockIdx.x, t = threadIdx.x;  // 256 threads
    __shared__ float r1[256], r2[256];
    __shared__ float stat[2];
    int j4 = t & 3, nb = t >> 2;
    float s1 = 0.f, s2 = 0.f;
    for (int n = nb; n < N_; n += 64) {
        float4 v = *(const float4*)(sx + ((size_t)n * PN_ + pn) * PL_ + j4 * 4);
        s1 += v.x + v.y + v.z + v.w;
        s2 += v.x * v.x + v.y * v.y + v.z * v.z + v.w * v.w;
    }
    r1[t] = s1; r2[t] = s2;
    __syncthreads();
    for (int st = 128; st > 0; st >>= 1) {
        if (t < st) { r1[t] += r1[t + st]; r2[t] += r2[t + st]; }
        __syncthreads();
    }
    if (t == 0) {
        float mu = r1[0] * (1.0f / (N_ * PL_));
        float var = r2[0] * (1.0f / (N_ * PL_)) - mu * mu;
        stat[0] = mu; stat[1] = rsqrtf(var + 1e-5f);
    }
    __syncthreads();
    float mu = stat[0], rstd = stat[1], gg = g[pn], bbv = bb[pn];
    for (int n = nb; n < N_; n += 64) {
        float* p = sx + ((size_t)n * PN_ + pn) * PL_ + j4 * 4;
        float4 v = *(const float4*)p;
        v.x = (v.x - mu) * rstd * gg + bbv;
        v.y = (v.y - mu) * rstd * gg + bbv;
        v.z = (v.z - mu) * rstd * gg + bbv;
        v.w = (v.w - mu) * rstd * gg + bbv;
        *(float4*)p = v;
    }
}

// ---------------------------------------------------------------- k_gemm
// C[M,N] = act(A[M,K] @ W[N,K]^T + bias); BM=BN=64, BK=16, 256 threads
template <int ACT>
__global__ void __launch_bounds__(256) k_gemm(const float* __restrict__ A,
                                              const float* __restrict__ W,
                                              const float* __restrict__ bias,
                                              float* __restrict__ Cout,
                                              int M, int Nn, int K) {
    __shared__ float at[16][68];
    __shared__ float wt[16][68];
    int bm = blockIdx.x * 64, bn = blockIdx.y * 64;
    int t = threadIdx.x;
    int tm = (t & 15) * 4, tn = (t >> 4) * 4;
    float acc[4][4] = {};
    int lm = t >> 2, lk = (t & 3) * 4;
    for (int k0 = 0; k0 < K; k0 += 16) {
        float4 av = *(const float4*)(A + (size_t)(bm + lm) * K + k0 + lk);
        float4 wv = *(const float4*)(W + (size_t)(bn + lm) * K + k0 + lk);
        __syncthreads();
        at[lk + 0][lm] = av.x; at[lk + 1][lm] = av.y;
        at[lk + 2][lm] = av.z; at[lk + 3][lm] = av.w;
        wt[lk + 0][lm] = wv.x; wt[lk + 1][lm] = wv.y;
        wt[lk + 2][lm] = wv.z; wt[lk + 3][lm] = wv.w;
        __syncthreads();
#pragma unroll
        for (int kk = 0; kk < 16; ++kk) {
            float4 a4 = *(const float4*)&at[kk][tm];
            float4 w4 = *(const float4*)&wt[kk][tn];
            acc[0][0] += a4.x * w4.x; acc[0][1] += a4.x * w4.y;
            acc[0][2] += a4.x * w4.z; acc[0][3] += a4.x * w4.w;
            acc[1][0] += a4.y * w4.x; acc[1][1] += a4.y * w4.y;
            acc[1][2] += a4.y * w4.z; acc[1][3] += a4.y * w4.w;
            acc[2][0] += a4.z * w4.x; acc[2][1] += a4.z * w4.y;
            acc[2][2] += a4.z * w4.z; acc[2][3] += a4.z * w4.w;
            acc[3][0] += a4.w * w4.x; acc[3][1] += a4.w * w4.y;
            acc[3][2] += a4.w * w4.z; acc[3][3] += a4.w * w4.w;
        }
    }
#pragma unroll
    for (int i = 0; i < 4; ++i) {
#pragma unroll
        for (int j = 0; j < 4; ++j) {
            float v = acc[i][j] + bias[bn + tn + j];
            if (ACT) v = geluf(v);
            Cout[(size_t)(bm + tm + i) * Nn + bn + tn + j] = v;
        }
    }
}

// ---------------------------------------------------------------- k_rowmlp4
__global__ void k_rowmlp4(const float* __restrict__ g3, const float* __restrict__ W4,
                          const float* __restrict__ b4, float* __restrict__ sxf) {
    int n = blockIdx.x, t = threadIdx.x;  // 128 threads
    __shared__ float row[192];
    for (int j = t; j < 192; j += 128) row[j] = g3[(size_t)n * 192 + j];
    __syncthreads();
    if (t < 96) {
        float a = b4[t];
        const float* wr = W4 + t * 192;
#pragma unroll 4
        for (int j = 0; j < 192; ++j) a += row[j] * wr[j];
        sxf[(size_t)n * 96 + t] = a;
    }
}

// ---------------------------------------------------------------- k_u
// u1(384) -> pairmean(192) -> LN1 -> W6(96) -> pairmean(48) -> LN2 -> W7(96)
__global__ void k_u(const float* __restrict__ u1, const float* __restrict__ ln1g,
                    const float* __restrict__ ln1b, const float* __restrict__ W6,
                    const float* __restrict__ b6, const float* __restrict__ ln2g,
                    const float* __restrict__ ln2b, const float* __restrict__ W7,
                    const float* __restrict__ b7, float* __restrict__ u3) {
    int n = blockIdx.x, t = threadIdx.x;  // 192 threads
    __shared__ float a[192];
    __shared__ float red1[256], red2[256];
    __shared__ float c2[48];
    __shared__ float stat[2];
    const float* ur = u1 + (size_t)n * 384;
    float av = 0.5f * (ur[2 * t] + ur[2 * t + 1]);
    red1[t] = av; red2[t] = av * av;
    if (t < 64) { red1[192 + t] = 0.f; red2[192 + t] = 0.f; }
    __syncthreads();
    for (int st = 128; st > 0; st >>= 1) {
        if (t < st) { red1[t] += red1[t + st]; red2[t] += red2[t + st]; }
        __syncthreads();
    }
    if (t == 0) {
        float mu = red1[0] * (1.0f / 192.0f);
        float var = red2[0] * (1.0f / 192.0f) - mu * mu;
        stat[0] = mu; stat[1] = rsqrtf(var + 1e-5f);
    }
    __syncthreads();
    a[t] = (av - stat[0]) * stat[1] * ln1g[t] + ln1b[t];
    __syncthreads();
    float bv = 0.f;
    if (t < 96) {
        bv = b6[t];
        const float* wr = W6 + t * 192;
#pragma unroll 4
        for (int j = 0; j < 192; ++j) bv += a[j] * wr[j];
    }
    __syncthreads();
    if (t < 96) red1[t] = bv;
    __syncthreads();
    float cv = 0.f;
    if (t < 48) cv = 0.5f * (red1[2 * t] + red1[2 * t + 1]);
    __syncthreads();
    if (t < 48) { red1[t] = cv; red2[t] = cv * cv; }
    else if (t < 64) { red1[t] = 0.f; red2[t] = 0.f; }
    __syncthreads();
    for (int st = 32; st > 0; st >>= 1) {
        if (t < st) { red1[t] += red1[t + st]; red2[t] += red2[t + st]; }
        __syncthreads();
    }
    if (t == 0) {
        float mu = red1[0] * (1.0f / 48.0f);
        float var = red2[0] * (1.0f / 48.0f) - mu * mu;
        stat[0] = mu; stat[1] = rsqrtf(var + 1e-5f);
    }
    __syncthreads();
    if (t < 48) c2[t] = (cv - stat[0]) * stat[1] * ln2g[t] + ln2b[t];
    __syncthreads();
    if (t < 96) {
        float acc = b7[t];
        const float* wr = W7 + t * 48;
#pragma unroll
        for (int j = 0; j < 48; ++j) acc += c2[j] * wr[j];
        u3[(size_t)n * 96 + t] = acc;
    }
}

// ---------------------------------------------------------------- k_fftconv
// low-pass (first 5 rfft bins) as 96-tap circular conv, then conv1d(3) + gelu add
__global__ void k_fftconv(const float* __restrict__ u3, const float* __restrict__ tw,
                          const float* __restrict__ tb, float* __restrict__ u4) {
    int b = blockIdx.x, t = threadIdx.x;  // 256 threads
    __shared__ float u[32][96];
    __shared__ float u2[32][96];
    __shared__ float w[96];
    for (int i = t; i < 32 * 96; i += 256)
        ((float*)u)[i] = u3[(size_t)b * 32 * 96 + i];
    if (t < 96) {
        float ang = 6.283185307179586f * (float)t / 96.0f;
        w[t] = (1.0f + 2.0f * (cosf(ang) + cosf(2.f * ang) + cosf(3.f * ang) + cosf(4.f * ang)))
               * (1.0f / 96.0f);
    }
    __syncthreads();
    for (int i = t; i < 32 * 96; i += 256) {
        int c = i / 96, x = i % 96;
        float acc = u[c][x];
        for (int mm = 0; mm < 96; ++mm) {
            int dd = x - mm; if (dd < 0) dd += 96;
            acc += u[c][mm] * w[dd];
        }
        u2[c][x] = acc;
    }
    __syncthreads();
    for (int i = t; i < 32 * 96; i += 256) {
        int oc = i / 96, x = i % 96;
        float acc = tb[oc];
        for (int ic = 0; ic < 32; ++ic) {
            const float* wv = tw + (oc * 32 + ic) * 3;
            float v0 = (x > 0)  ? u2[ic][x - 1] : 0.f;
            float v1 = u2[ic][x];
            float v2 = (x < 95) ? u2[ic][x + 1] : 0.f;
            acc += v0 * wv[0] + v1 * wv[1] + v2 * wv[2];
        }
        u4[(size_t)b * 32 * 96 + i] = u2[oc][x] + geluf(acc);
    }
}

// ---------------------------------------------------------------- k_out
// x = [sxf | u4] @ W8^T + b8 ; write transposed to (B, PRED, C)
__global__ void k_out(const float* __restrict__ sxf, const float* __restrict__ u4,
                      const float* __restrict__ W8, const float* __restrict__ b8,
                      float* __restrict__ out) {
    int b = blockIdx.x, t = threadIdx.x;  // 256 threads
    __shared__ float ld[32][193];
    for (int i = t; i < 32 * 96; i += 256) {
        int c = i / 96, j = i % 96;
        ld[c][j]      = sxf[((size_t)(b * 32 + c)) * 96 + j];
        ld[c][96 + j] = u4[((size_t)(b * 32 + c)) * 96 + j];
    }
    __syncthreads();
    for (int i = t; i < 96 * 32; i += 256) {
        int o = i >> 5, c = i & 31;
        float acc = b8[o];
        const float* wr = W8 + o * 192;
#pragma unroll 4
        for (int j = 0; j < 192; ++j) acc += ld[c][j] * wr[j];
        out[((size_t)b * 96 + o) * 32 + c] = acc;
    }
}

// ---------------------------------------------------------------- launch
extern "C" void kernel_launch(void* const* d_in, const int* in_sizes, int n_in,
                              void* d_out, int out_size, void* d_ws, size_t ws_size,
                              hipStream_t stream) {
    const float* s    = (const float*)d_in[0];
    const float* t    = (const float*)d_in[1];
    const int*   cyc  = (const int*)d_in[2];
    const float* rw1  = (const float*)d_in[3];
    const float* rb1  = (const float*)d_in[4];
    const float* rw2  = (const float*)d_in[5];
    const float* rb2  = (const float*)d_in[6];
    const float* A0   = (const float*)d_in[7];
    const float* A1   = (const float*)d_in[8];
    const float* A2   = (const float*)d_in[9];
    const float* P0   = (const float*)d_in[10];
    const float* P1   = (const float*)d_in[11];
    const float* P2   = (const float*)d_in[12];
    const float* Wqkv = (const float*)d_in[13];
    const float* bqkv = (const float*)d_in[14];
    const float* Wo   = (const float*)d_in[15];
    const float* bo   = (const float*)d_in[16];
    const float* alpha= (const float*)d_in[17];
    const float* bn_g = (const float*)d_in[18];
    const float* bn_b = (const float*)d_in[19];
    const float* W3   = (const float*)d_in[20];
    const float* b3   = (const float*)d_in[21];
    const float* W4   = (const float*)d_in[22];
    const float* b4   = (const float*)d_in[23];
    const float* W5   = (const float*)d_in[24];
    const float* b5   = (const float*)d_in[25];
    const float* W6   = (const float*)d_in[26];
    const float* b6   = (const float*)d_in[27];
    const float* W7   = (const float*)d_in[28];
    const float* b7   = (const float*)d_in[29];
    const float* W8   = (const float*)d_in[30];
    const float* b8   = (const float*)d_in[31];
    const float* ln1g = (const float*)d_in[32];
    const float* ln1b = (const float*)d_in[33];
    const float* ln2g = (const float*)d_in[34];
    const float* ln2b = (const float*)d_in[35];
    const float* tew  = (const float*)d_in[36];
    const float* teb  = (const float*)d_in[37];

    float* ws   = (float*)d_ws;
    float* wp   = ws;                    // 192
    float* phis = wp + 192;              // 4096
    float* wcs  = phis + 4096;           // 3*64*32*512 = 3145728
    float* srow = wcs + 3145728;         // 1048576
    float* trow = srow + 1048576;        // 1048576
    float* sx   = trow + 1048576;        // 2097152
    float* g3   = sx + 2097152;          // 393216
    float* sxf  = g3 + 393216;           // 196608
    float* u1   = sxf + 196608;          // 786432
    float* u3f  = u1 + 786432;           // 196608
    float* u4f  = u3f + 196608;          // 196608
    float* out  = (float*)d_out;

    k_head<<<64, 256, 0, stream>>>(s, rw1, rb1, rw2, rb2, wp);
    k_phi<<<64, 128, 0, stream>>>(P0, P1, P2, cyc, wp, phis);
    k_attn<<<dim3(4, 3, 64), 128, 0, stream>>>(s, cyc, A0, A1, A2, P0, P1, P2, wp, wcs);
    k_combine<<<4096, 256, 0, stream>>>(s, t, wcs, srow, trow);
    k_patch<<<2048, 64, 0, stream>>>(srow, phis, Wqkv, bqkv, Wo, bo, alpha, sx);
    k_bn<<<64, 256, 0, stream>>>(sx, bn_g, bn_b);
    k_gemm<1><<<dim3(32, 3), 256, 0, stream>>>(sx, W3, b3, g3, 2048, 192, 1024);
    k_rowmlp4<<<2048, 128, 0, stream>>>(g3, W4, b4, sxf);
    k_gemm<0><<<dim3(32, 6), 256, 0, stream>>>(trow, W5, b5, u1, 2048, 384, 512);
    k_u<<<2048, 192, 0, stream>>>(u1, ln1g, ln1b, W6, b6, ln2g, ln2b, W7, b7, u3f);
    k_fftconv<<<64, 256, 0, stream>>>(u3f, tew, teb, u4f);
    k_out<<<64, 256, 0, stream>>>(sxf, u4f, W8, b8, out);
}

// Round 2
// 565.972 us; speedup vs baseline: 1.5510x; 1.5510x over previous
//
#include <hip/hip_runtime.h>
#include <math.h>

#define B_    64
#define I_    512
#define C_    32
#define PRED_ 96
#define PL_   16
#define ST_   8
#define NH_   8
#define PN_   64
#define N_    2048

__device__ __forceinline__ float geluf(float x) {
    return 0.5f * x * (1.0f + erff(x * 0.70710678118654752f));
}
__device__ __forceinline__ float softplusf(float x) {
    return fmaxf(x, 0.0f) + log1pf(__expf(-fabsf(x)));
}

// ---------------------------------------------------------------- k_head
__global__ void k_head(const float* __restrict__ s, const float* __restrict__ rw1,
                       const float* __restrict__ rb1, const float* __restrict__ rw2,
                       const float* __restrict__ rb2, float* __restrict__ wp) {
    int b = blockIdx.x, t = threadIdx.x;  // 256 threads
    __shared__ float part[8][32];
    __shared__ float smean[32];
    __shared__ float h[16];
    int c = t & 31, chunk = t >> 5;
    float acc = 0.f;
    for (int l = chunk * 64; l < chunk * 64 + 64; ++l)
        acc += s[((size_t)b * I_ + l) * C_ + c];
    part[chunk][c] = acc;
    __syncthreads();
    if (t < 32) {
        float v = 0.f;
#pragma unroll
        for (int i = 0; i < 8; ++i) v += part[i][t];
        smean[t] = v * (1.0f / I_);
    }
    __syncthreads();
    if (t < 16) {
        float a = rb1[t];
#pragma unroll
        for (int c2 = 0; c2 < 32; ++c2) a += smean[c2] * rw1[t * 32 + c2];
        h[t] = geluf(a);
    }
    __syncthreads();
    if (t == 0) {
        float lg[3], mx = -1e30f;
        for (int k = 0; k < 3; ++k) {
            float a = rb2[k];
            for (int j = 0; j < 16; ++j) a += h[j] * rw2[k * 16 + j];
            lg[k] = a; mx = fmaxf(mx, a);
        }
        float d = 0.f;
        for (int k = 0; k < 3; ++k) { lg[k] = __expf(lg[k] - mx); d += lg[k]; }
        float inv = 1.f / d;
        for (int k = 0; k < 3; ++k) wp[b * 3 + k] = lg[k] * inv;
    }
}

// ---------------------------------------------------------------- k_phi
__global__ void k_phi(const float* __restrict__ P0, const float* __restrict__ P1,
                      const float* __restrict__ P2, const int* __restrict__ cyc,
                      const float* __restrict__ wp, float* __restrict__ phis) {
    int b = blockIdx.x, t = threadIdx.x;  // 128 threads
    __shared__ float pm[I_];
    float p0 = wp[b * 3 + 0], p1 = wp[b * 3 + 1], p2 = wp[b * 3 + 2];
    int cy = cyc[b];
    for (int l = t; l < I_; l += 128) {
        float acc = 0.f;
        {
            int idx = (cy + l) % 24;
            const float4* r = (const float4*)(P0 + idx * 32);
            float s4 = 0.f;
#pragma unroll
            for (int i = 0; i < 8; ++i) { float4 v = r[i]; s4 += v.x + v.y + v.z + v.w; }
            acc += p0 * s4;
        }
        {
            int idx = (cy + l) % 168;
            const float4* r = (const float4*)(P1 + idx * 32);
            float s4 = 0.f;
#pragma unroll
            for (int i = 0; i < 8; ++i) { float4 v = r[i]; s4 += v.x + v.y + v.z + v.w; }
            acc += p1 * s4;
        }
        {
            int idx = (cy + l) % 336;
            const float4* r = (const float4*)(P2 + idx * 32);
            float s4 = 0.f;
#pragma unroll
            for (int i = 0; i < 8; ++i) { float4 v = r[i]; s4 += v.x + v.y + v.z + v.w; }
            acc += p2 * s4;
        }
        pm[l] = acc * (1.0f / 32.0f);
    }
    __syncthreads();
    if (t < PN_) {
        float sum = 0.f;
#pragma unroll
        for (int j = 0; j < 16; ++j) {
            int l = t * ST_ + j; if (l > 511) l = 511;
            sum += pm[l];
        }
        phis[b * PN_ + t] = sum * (1.0f / 16.0f);
    }
}

// ---------------------------------------------------------------- k_attn
// Single-pass unnormalized softmax (no max needed: |S| <~ 4), kk-split in 2.
// Partial d and cs per (h = k3*2+kh, b, l) written to ws.
__global__ void __launch_bounds__(256) k_attn(
        const float* __restrict__ s, const int* __restrict__ cyc,
        const float* __restrict__ A0, const float* __restrict__ A1, const float* __restrict__ A2,
        const float* __restrict__ P0, const float* __restrict__ P1, const float* __restrict__ P2,
        float* __restrict__ pd, float* __restrict__ pcs) {
    int qh = blockIdx.x & 1, kh = blockIdx.x >> 1;
    int l = qh * 256 + threadIdx.x;
    int k3 = blockIdx.y, b = blockIdx.z;
    const float* Atab; const float* Ptab; int Wk;
    if (k3 == 0)      { Atab = A0; Ptab = P0; Wk = 24;  }
    else if (k3 == 1) { Atab = A1; Ptab = P1; Wk = 168; }
    else              { Atab = A2; Ptab = P2; Wk = 336; }
    int idx = (cyc[b] + l) % Wk;
    float4 qr[8];
    {
        const float4* Ar = (const float4*)(Atab + idx * 32);
        const float4* Pr = (const float4*)(Ptab + idx * 32);
#pragma unroll
        for (int i = 0; i < 8; ++i) {
            float4 a = Ar[i], p = Pr[i];
            float4 q;
            q.x = softplusf(a.x) * __cosf(p.x);
            q.y = softplusf(a.y) * __cosf(p.y);
            q.z = softplusf(a.z) * __cosf(p.z);
            q.w = softplusf(a.w) * __cosf(p.w);
            qr[i] = q;
        }
    }
    const float4* sb = (const float4*)(s + ((size_t)b * I_ + kh * 256) * C_);
    const float rs = 0.17677669529663687f;  // 1/sqrt(32)
    float d = 0.f;
    float4 cs[8];
#pragma unroll
    for (int i = 0; i < 8; ++i) cs[i] = make_float4(0.f, 0.f, 0.f, 0.f);
#pragma unroll 2
    for (int kk = 0; kk < 256; ++kk) {
        const float4* srow = sb + kk * 8;
        float4 sv[8];
        float acc = 0.f;
#pragma unroll
        for (int i = 0; i < 8; ++i) {
            sv[i] = srow[i];
            acc += qr[i].x * sv[i].x + qr[i].y * sv[i].y + qr[i].z * sv[i].z + qr[i].w * sv[i].w;
        }
        float w = __expf(acc * rs);
        d += w;
#pragma unroll
        for (int i = 0; i < 8; ++i) {
            cs[i].x += w * sv[i].x; cs[i].y += w * sv[i].y;
            cs[i].z += w * sv[i].z; cs[i].w += w * sv[i].w;
        }
    }
    int h = k3 * 2 + kh;
    pd[((size_t)h * B_ + b) * I_ + l] = d;
    float* outp = pcs + (((size_t)h * B_ + b) * C_) * I_ + l;
#pragma unroll
    for (int i = 0; i < 8; ++i) {
        outp[(size_t)(i * 4 + 0) * I_] = cs[i].x;
        outp[(size_t)(i * 4 + 1) * I_] = cs[i].y;
        outp[(size_t)(i * 4 + 2) * I_] = cs[i].z;
        outp[(size_t)(i * 4 + 3) * I_] = cs[i].w;
    }
}

// ---------------------------------------------------------------- k_combine
// Merge softmax halves, add to s, transpose (b,l,c)->(n,l); also transpose t.
// grid (64, 16), 256 threads; tile = 32 l x 32 c.
__global__ void k_combine(const float* __restrict__ s, const float* __restrict__ t,
                          const float* __restrict__ pd, const float* __restrict__ pcs,
                          const float* __restrict__ wp,
                          float* __restrict__ srow, float* __restrict__ trow) {
    int b = blockIdx.x, l0 = blockIdx.y * 32;
    int tt_ = threadIdx.x;
    __shared__ float st[32][33], tl[32][33];
    __shared__ float rw[3][32];
#pragma unroll
    for (int r = 0; r < 4; ++r) {
        int lin = r * 256 + tt_;
        int lq = lin >> 5, c = lin & 31;
        st[lq][c] = s[((size_t)b * I_ + l0 + lq) * C_ + c];
        tl[lq][c] = t[((size_t)b * I_ + l0 + lq) * C_ + c];
    }
    if (tt_ < 96) {
        int k3 = tt_ >> 5, lq = tt_ & 31;
        float d = pd[((size_t)(k3 * 2 + 0) * B_ + b) * I_ + l0 + lq]
                + pd[((size_t)(k3 * 2 + 1) * B_ + b) * I_ + l0 + lq];
        rw[k3][lq] = wp[b * 3 + k3] / d;
    }
    __syncthreads();
#pragma unroll
    for (int r = 0; r < 4; ++r) {
        int lin = r * 256 + tt_;
        int co = lin >> 5, lo = lin & 31;
        float sum = 0.f;
#pragma unroll
        for (int k3 = 0; k3 < 3; ++k3) {
            float v = pcs[(((size_t)(k3 * 2 + 0) * B_ + b) * C_ + co) * I_ + l0 + lo]
                    + pcs[(((size_t)(k3 * 2 + 1) * B_ + b) * C_ + co) * I_ + l0 + lo];
            sum += rw[k3][lo] * v;
        }
        size_t oi = ((size_t)(b * C_ + co)) * I_ + l0 + lo;
        srow[oi] = st[lo][co] + sum;
        trow[oi] = tl[lo][co];
    }
}

// ---------------------------------------------------------------- k_patch
__global__ void __launch_bounds__(64) k_patch(
        const float* __restrict__ srow, const float* __restrict__ phis,
        const float* __restrict__ Wqkv, const float* __restrict__ bqkv,
        const float* __restrict__ Wo, const float* __restrict__ bo,
        const float* __restrict__ alpha_p, float* __restrict__ sx) {
    int n = blockIdx.x, t = threadIdx.x;  // 64 threads, t = patch index
    int b = n >> 5;
    __shared__ float klds[64][16];
    __shared__ float vlds[64][16];
    __shared__ float blds[64][65];
    __shared__ float phil[64];
    float alpha = alpha_p[0];
    float sp[16];
    const float* srn = srow + (size_t)n * I_;
#pragma unroll
    for (int j = 0; j < 16; ++j) {
        int l = t * ST_ + j; if (l > 511) l = 511;
        sp[j] = srn[l];
    }
    phil[t] = phis[b * PN_ + t];
    __syncthreads();
    float phit = phil[t];
    for (int ss = 0; ss < 64; ++ss) blds[t][ss] = alpha * __cosf(phit - phil[ss]);
    float q[16];
#pragma unroll
    for (int o = 0; o < 16; ++o) {
        float a = bqkv[o], ka = bqkv[16 + o], va = bqkv[32 + o];
#pragma unroll
        for (int i2 = 0; i2 < 16; ++i2) {
            float spv = sp[i2];
            a  += spv * Wqkv[o * 16 + i2];
            ka += spv * Wqkv[(16 + o) * 16 + i2];
            va += spv * Wqkv[(32 + o) * 16 + i2];
        }
        q[o] = a; klds[t][o] = ka; vlds[t][o] = va;
    }
    __syncthreads();
    const float rs2 = 0.70710678118654752f;
    float o2in[16];
#pragma unroll
    for (int h = 0; h < 8; ++h) {
        float q0 = q[2 * h], q1 = q[2 * h + 1];
        float mh = -1e30f;
        for (int ss = 0; ss < 64; ++ss) {
            float sc = (q0 * klds[ss][2 * h] + q1 * klds[ss][2 * h + 1]) * rs2 + blds[t][ss];
            mh = fmaxf(mh, sc);
        }
        float dh = 0.f, o0 = 0.f, o1 = 0.f;
        for (int ss = 0; ss < 64; ++ss) {
            float sc = (q0 * klds[ss][2 * h] + q1 * klds[ss][2 * h + 1]) * rs2 + blds[t][ss];
            float w = __expf(sc - mh);
            dh += w; o0 += w * vlds[ss][2 * h]; o1 += w * vlds[ss][2 * h + 1];
        }
        float inv = 1.f / dh;
        o2in[2 * h] = o0 * inv; o2in[2 * h + 1] = o1 * inv;
    }
    float* sxr = sx + ((size_t)n * PN_ + t) * PL_;
#pragma unroll
    for (int i2 = 0; i2 < 16; ++i2) {
        float a = bo[i2];
#pragma unroll
        for (int j = 0; j < 16; ++j) a += o2in[j] * Wo[i2 * 16 + j];
        sxr[i2] = geluf(sp[i2] + a);
    }
}

// ---------------------------------------------------------------- k_bn_stats
// grid (64 pn, 4 chunks), 256 thr; partial (sum, sumsq) per (pn, chunk)
__global__ void k_bn_stats(const float* __restrict__ sx, float* __restrict__ bnpart) {
    int pn = blockIdx.x, chunk = blockIdx.y, t = threadIdx.x;
    __shared__ float r1[256], r2[256];
    int j4 = t & 3, nb = t >> 2;
    float s1 = 0.f, s2 = 0.f;
    for (int i = 0; i < 8; ++i) {
        int n = chunk * 512 + nb + i * 64;
        float4 v = *(const float4*)(sx + ((size_t)n * PN_ + pn) * PL_ + j4 * 4);
        s1 += v.x + v.y + v.z + v.w;
        s2 += v.x * v.x + v.y * v.y + v.z * v.z + v.w * v.w;
    }
    r1[t] = s1; r2[t] = s2;
    __syncthreads();
    for (int st = 128; st > 0; st >>= 1) {
        if (t < st) { r1[t] += r1[t + st]; r2[t] += r2[t + st]; }
        __syncthreads();
    }
    if (t == 0) {
        bnpart[(pn * 4 + chunk) * 2 + 0] = r1[0];
        bnpart[(pn * 4 + chunk) * 2 + 1] = r2[0];
    }
}

// ---------------------------------------------------------------- k_bn_apply
__global__ void k_bn_apply(float* __restrict__ sx, const float* __restrict__ bnpart,
                           const float* __restrict__ g, const float* __restrict__ bb) {
    int g4 = blockIdx.x * 256 + threadIdx.x;  // float4 index
    int pn = (g4 >> 2) & 63;
    float s1 = 0.f, s2 = 0.f;
#pragma unroll
    for (int ch = 0; ch < 4; ++ch) {
        s1 += bnpart[(pn * 4 + ch) * 2 + 0];
        s2 += bnpart[(pn * 4 + ch) * 2 + 1];
    }
    const float inv = 1.0f / (N_ * PL_);
    float mu = s1 * inv;
    float var = s2 * inv - mu * mu;
    float rstd = rsqrtf(var + 1e-5f);
    float gg = g[pn], bbv = bb[pn];
    float4* p = (float4*)sx + g4;
    float4 v = *p;
    v.x = (v.x - mu) * rstd * gg + bbv;
    v.y = (v.y - mu) * rstd * gg + bbv;
    v.z = (v.z - mu) * rstd * gg + bbv;
    v.w = (v.w - mu) * rstd * gg + bbv;
    *p = v;
}

// ---------------------------------------------------------------- k_gemm32
// C[M,N] = act(A[M,K] @ W[N,K]^T + bias); BM=BN=32, BK=32, 128 threads
template <int ACT>
__global__ void __launch_bounds__(128) k_gemm32(const float* __restrict__ A,
                                                const float* __restrict__ W,
                                                const float* __restrict__ bias,
                                                float* __restrict__ Cout,
                                                int M, int Nn, int K) {
    __shared__ float at[32][36];
    __shared__ float wt[32][36];
    int bm = blockIdx.x * 32, bn = blockIdx.y * 32;
    int t = threadIdx.x;
    int lr = t >> 2, lk = (t & 3) * 8;
    int tm = (t & 15) * 2, tn = (t >> 4) * 4;
    float acc[2][4] = {};
    for (int k0 = 0; k0 < K; k0 += 32) {
        float4 a0 = *(const float4*)(A + (size_t)(bm + lr) * K + k0 + lk);
        float4 a1 = *(const float4*)(A + (size_t)(bm + lr) * K + k0 + lk + 4);
        float4 w0 = *(const float4*)(W + (size_t)(bn + lr) * K + k0 + lk);
        float4 w1 = *(const float4*)(W + (size_t)(bn + lr) * K + k0 + lk + 4);
        __syncthreads();
        at[lk + 0][lr] = a0.x; at[lk + 1][lr] = a0.y; at[lk + 2][lr] = a0.z; at[lk + 3][lr] = a0.w;
        at[lk + 4][lr] = a1.x; at[lk + 5][lr] = a1.y; at[lk + 6][lr] = a1.z; at[lk + 7][lr] = a1.w;
        wt[lk + 0][lr] = w0.x; wt[lk + 1][lr] = w0.y; wt[lk + 2][lr] = w0.z; wt[lk + 3][lr] = w0.w;
        wt[lk + 4][lr] = w1.x; wt[lk + 5][lr] = w1.y; wt[lk + 6][lr] = w1.z; wt[lk + 7][lr] = w1.w;
        __syncthreads();
#pragma unroll
        for (int kk = 0; kk < 32; ++kk) {
            float2 a2 = *(const float2*)&at[kk][tm];
            float4 w4 = *(const float4*)&wt[kk][tn];
            acc[0][0] += a2.x * w4.x; acc[0][1] += a2.x * w4.y;
            acc[0][2] += a2.x * w4.z; acc[0][3] += a2.x * w4.w;
            acc[1][0] += a2.y * w4.x; acc[1][1] += a2.y * w4.y;
            acc[1][2] += a2.y * w4.z; acc[1][3] += a2.y * w4.w;
        }
    }
#pragma unroll
    for (int i = 0; i < 2; ++i) {
#pragma unroll
        for (int j = 0; j < 4; ++j) {
            float v = acc[i][j] + bias[bn + tn + j];
            if (ACT) v = geluf(v);
            Cout[(size_t)(bm + tm + i) * Nn + bn + tn + j] = v;
        }
    }
}

// ---------------------------------------------------------------- k_rowmlp4
__global__ void k_rowmlp4(const float* __restrict__ g3, const float* __restrict__ W4,
                          const float* __restrict__ b4, float* __restrict__ sxf) {
    int n = blockIdx.x, t = threadIdx.x;  // 128 threads
    __shared__ float row[192];
    for (int j = t; j < 192; j += 128) row[j] = g3[(size_t)n * 192 + j];
    __syncthreads();
    if (t < 96) {
        float a = b4[t];
        const float* wr = W4 + t * 192;
#pragma unroll 4
        for (int j = 0; j < 192; ++j) a += row[j] * wr[j];
        sxf[(size_t)n * 96 + t] = a;
    }
}

// ---------------------------------------------------------------- k_u
__global__ void k_u(const float* __restrict__ u1, const float* __restrict__ ln1g,
                    const float* __restrict__ ln1b, const float* __restrict__ W6,
                    const float* __restrict__ b6, const float* __restrict__ ln2g,
                    const float* __restrict__ ln2b, const float* __restrict__ W7,
                    const float* __restrict__ b7, float* __restrict__ u3) {
    int n = blockIdx.x, t = threadIdx.x;  // 192 threads
    __shared__ float a[192];
    __shared__ float red1[256], red2[256];
    __shared__ float c2[48];
    __shared__ float stat[2];
    const float* ur = u1 + (size_t)n * 384;
    float av = 0.5f * (ur[2 * t] + ur[2 * t + 1]);
    red1[t] = av; red2[t] = av * av;
    if (t < 64) { red1[192 + t] = 0.f; red2[192 + t] = 0.f; }
    __syncthreads();
    for (int st = 128; st > 0; st >>= 1) {
        if (t < st) { red1[t] += red1[t + st]; red2[t] += red2[t + st]; }
        __syncthreads();
    }
    if (t == 0) {
        float mu = red1[0] * (1.0f / 192.0f);
        float var = red2[0] * (1.0f / 192.0f) - mu * mu;
        stat[0] = mu; stat[1] = rsqrtf(var + 1e-5f);
    }
    __syncthreads();
    a[t] = (av - stat[0]) * stat[1] * ln1g[t] + ln1b[t];
    __syncthreads();
    float bv = 0.f;
    if (t < 96) {
        bv = b6[t];
        const float* wr = W6 + t * 192;
#pragma unroll 4
        for (int j = 0; j < 192; ++j) bv += a[j] * wr[j];
    }
    __syncthreads();
    if (t < 96) red1[t] = bv;
    __syncthreads();
    float cv = 0.f;
    if (t < 48) cv = 0.5f * (red1[2 * t] + red1[2 * t + 1]);
    __syncthreads();
    if (t < 48) { red1[t] = cv; red2[t] = cv * cv; }
    else if (t < 64) { red1[t] = 0.f; red2[t] = 0.f; }
    __syncthreads();
    for (int st = 32; st > 0; st >>= 1) {
        if (t < st) { red1[t] += red1[t + st]; red2[t] += red2[t + st]; }
        __syncthreads();
    }
    if (t == 0) {
        float mu = red1[0] * (1.0f / 48.0f);
        float var = red2[0] * (1.0f / 48.0f) - mu * mu;
        stat[0] = mu; stat[1] = rsqrtf(var + 1e-5f);
    }
    __syncthreads();
    if (t < 48) c2[t] = (cv - stat[0]) * stat[1] * ln2g[t] + ln2b[t];
    __syncthreads();
    if (t < 96) {
        float acc = b7[t];
        const float* wr = W7 + t * 48;
#pragma unroll
        for (int j = 0; j < 48; ++j) acc += c2[j] * wr[j];
        u3[(size_t)n * 96 + t] = acc;
    }
}

// ---------------------------------------------------------------- k_lowpass
// circular 96-tap Dirichlet conv; grid 256 blocks x 8 rows
__global__ void k_lowpass(const float* __restrict__ u3, float* __restrict__ u2out) {
    int t = threadIdx.x;
    int row0 = blockIdx.x * 8;
    __shared__ float ul[8][96];
    __shared__ float w2[192];
    for (int i = t; i < 768; i += 256)
        ((float*)ul)[i] = u3[(size_t)row0 * 96 + i];
    if (t < 192) {
        float ang = 6.283185307179586f * (float)(t % 96) / 96.0f;
        w2[t] = (1.0f + 2.0f * (__cosf(ang) + __cosf(2.f * ang) + __cosf(3.f * ang) + __cosf(4.f * ang)))
                * (1.0f / 96.0f);
    }
    __syncthreads();
    for (int i = t; i < 768; i += 256) {
        int rl = i / 96, x = i % 96;
        float acc = ul[rl][x];
#pragma unroll 4
        for (int mm = 0; mm < 96; ++mm)
            acc += ul[rl][mm] * w2[x - mm + 96];
        u2out[(size_t)row0 * 96 + i] = acc;
    }
}

// ---------------------------------------------------------------- k_conv
// conv1d(32->32, k=3, zero pad) + residual + gelu; grid (64 b, 4 xq)
__global__ void k_conv(const float* __restrict__ u2, const float* __restrict__ tw,
                       const float* __restrict__ tb, float* __restrict__ u4) {
    int b = blockIdx.x, xq = blockIdx.y, t = threadIdx.x;
    int x0 = xq * 24;
    __shared__ float ub[32][26];
    __shared__ float twl[3072];
    for (int i = t; i < 832; i += 256) {
        int ic = i / 26, xx = i % 26;
        int gx = x0 + xx - 1;
        ub[ic][xx] = (gx >= 0 && gx < 96) ? u2[((size_t)b * 32 + ic) * 96 + gx] : 0.f;
    }
    for (int i = t; i < 3072; i += 256) twl[i] = tw[i];
    __syncthreads();
    for (int i = t; i < 768; i += 256) {
        int oc = i / 24, xx = i % 24;
        float acc = tb[oc];
#pragma unroll 8
        for (int ic = 0; ic < 32; ++ic) {
            const float* wv = twl + (oc * 32 + ic) * 3;
            acc += ub[ic][xx] * wv[0] + ub[ic][xx + 1] * wv[1] + ub[ic][xx + 2] * wv[2];
        }
        u4[((size_t)b * 32 + oc) * 96 + x0 + xx] = ub[oc][xx + 1] + geluf(acc);
    }
}

// ---------------------------------------------------------------- k_out
// x = [sxf | u4] @ W8^T + b8 ; grid (64 b, 4 oq)
__global__ void k_out(const float* __restrict__ sxf, const float* __restrict__ u4,
                      const float* __restrict__ W8, const float* __restrict__ b8,
                      float* __restrict__ out) {
    int b = blockIdx.x, oq = blockIdx.y, t = threadIdx.x;
    __shared__ float ld[32][193];
    for (int i = t; i < 32 * 96; i += 256) {
        int c = i / 96, j = i % 96;
        ld[c][j]      = sxf[((size_t)(b * 32 + c)) * 96 + j];
        ld[c][96 + j] = u4[((size_t)(b * 32 + c)) * 96 + j];
    }
    __syncthreads();
    for (int i = t; i < 24 * 32; i += 256) {
        int o = oq * 24 + (i >> 5), c = i & 31;
        float acc = b8[o];
        const float* wr = W8 + o * 192;
#pragma unroll 4
        for (int j = 0; j < 192; ++j) acc += ld[c][j] * wr[j];
        out[((size_t)b * 96 + o) * 32 + c] = acc;
    }
}

// ---------------------------------------------------------------- launch
extern "C" void kernel_launch(void* const* d_in, const int* in_sizes, int n_in,
                              void* d_out, int out_size, void* d_ws, size_t ws_size,
                              hipStream_t stream) {
    const float* s    = (const float*)d_in[0];
    const float* t    = (const float*)d_in[1];
    const int*   cyc  = (const int*)d_in[2];
    const float* rw1  = (const float*)d_in[3];
    const float* rb1  = (const float*)d_in[4];
    const float* rw2  = (const float*)d_in[5];
    const float* rb2  = (const float*)d_in[6];
    const float* A0   = (const float*)d_in[7];
    const float* A1   = (const float*)d_in[8];
    const float* A2   = (const float*)d_in[9];
    const float* P0   = (const float*)d_in[10];
    const float* P1   = (const float*)d_in[11];
    const float* P2   = (const float*)d_in[12];
    const float* Wqkv = (const float*)d_in[13];
    const float* bqkv = (const float*)d_in[14];
    const float* Wo   = (const float*)d_in[15];
    const float* bo   = (const float*)d_in[16];
    const float* alpha= (const float*)d_in[17];
    const float* bn_g = (const float*)d_in[18];
    const float* bn_b = (const float*)d_in[19];
    const float* W3   = (const float*)d_in[20];
    const float* b3   = (const float*)d_in[21];
    const float* W4   = (const float*)d_in[22];
    const float* b4   = (const float*)d_in[23];
    const float* W5   = (const float*)d_in[24];
    const float* b5   = (const float*)d_in[25];
    const float* W6   = (const float*)d_in[26];
    const float* b6   = (const float*)d_in[27];
    const float* W7   = (const float*)d_in[28];
    const float* b7   = (const float*)d_in[29];
    const float* W8   = (const float*)d_in[30];
    const float* b8   = (const float*)d_in[31];
    const float* ln1g = (const float*)d_in[32];
    const float* ln1b = (const float*)d_in[33];
    const float* ln2g = (const float*)d_in[34];
    const float* ln2b = (const float*)d_in[35];
    const float* tew  = (const float*)d_in[36];
    const float* teb  = (const float*)d_in[37];

    float* ws     = (float*)d_ws;
    float* wp     = ws;                         // 192
    float* phis   = ws + 192;                   // 4096
    float* bnpart = ws + 4288;                  // 512
    float* srow   = ws + 4864;                  // 1048576
    float* trow   = srow + 1048576;             // 1048576
    float* R      = trow + 1048576;             // big overlay region
    // phase 1 overlay: partial softmax
    float* pd  = R;                             // 6*64*512   = 196608
    float* pcs = R + 196608;                    // 6*64*32*512 = 6291456
    // phase 2 overlay (after k_combine consumed pd/pcs):
    float* sx  = R;                             // 2097152
    float* g3  = R + 2097152;                   // 393216
    float* sxf = R + 2490368;                   // 196608
    float* u1  = R + 2686976;                   // 786432
    float* u3f = R + 3473408;                   // 196608
    float* u2f = R + 3670016;                   // 196608
    float* u4f = R + 3866624;                   // 196608
    float* out = (float*)d_out;

    k_head<<<64, 256, 0, stream>>>(s, rw1, rb1, rw2, rb2, wp);
    k_phi<<<64, 128, 0, stream>>>(P0, P1, P2, cyc, wp, phis);
    k_attn<<<dim3(4, 3, 64), 256, 0, stream>>>(s, cyc, A0, A1, A2, P0, P1, P2, pd, pcs);
    k_combine<<<dim3(64, 16), 256, 0, stream>>>(s, t, pd, pcs, wp, srow, trow);
    k_patch<<<2048, 64, 0, stream>>>(srow, phis, Wqkv, bqkv, Wo, bo, alpha, sx);
    k_bn_stats<<<dim3(64, 4), 256, 0, stream>>>(sx, bnpart);
    k_bn_apply<<<2048, 256, 0, stream>>>(sx, bnpart, bn_g, bn_b);
    k_gemm32<1><<<dim3(64, 6), 128, 0, stream>>>(sx, W3, b3, g3, 2048, 192, 1024);
    k_rowmlp4<<<2048, 128, 0, stream>>>(g3, W4, b4, sxf);
    k_gemm32<0><<<dim3(64, 12), 128, 0, stream>>>(trow, W5, b5, u1, 2048, 384, 512);
    k_u<<<2048, 192, 0, stream>>>(u1, ln1g, ln1b, W6, b6, ln2g, ln2b, W7, b7, u3f);
    k_lowpass<<<256, 256, 0, stream>>>(u3f, u2f);
    k_conv<<<dim3(64, 4), 256, 0, stream>>>(u2f, tew, teb, u4f);
    k_out<<<dim3(64, 4), 256, 0, stream>>>(sxf, u4f, W8, b8, out);
}

// Round 3
// 466.859 us; speedup vs baseline: 1.8803x; 1.2123x over previous
//
#include <hip/hip_runtime.h>
#include <math.h>

#define B_    64
#define I_    512
#define C_    32
#define PRED_ 96
#define PL_   16
#define ST_   8
#define NH_   8
#define PN_   64
#define N_    2048

__device__ __forceinline__ float geluf(float x) {
    return 0.5f * x * (1.0f + erff(x * 0.70710678118654752f));
}
__device__ __forceinline__ float softplusf(float x) {
    return fmaxf(x, 0.0f) + log1pf(__expf(-fabsf(x)));
}

// ---------------------------------------------------------------- k_head
__global__ void k_head(const float* __restrict__ s, const float* __restrict__ rw1,
                       const float* __restrict__ rb1, const float* __restrict__ rw2,
                       const float* __restrict__ rb2, float* __restrict__ wp) {
    int b = blockIdx.x, t = threadIdx.x;  // 256 threads
    __shared__ float part[8][32];
    __shared__ float smean[32];
    __shared__ float h[16];
    int c = t & 31, chunk = t >> 5;
    float acc = 0.f;
    for (int l = chunk * 64; l < chunk * 64 + 64; ++l)
        acc += s[((size_t)b * I_ + l) * C_ + c];
    part[chunk][c] = acc;
    __syncthreads();
    if (t < 32) {
        float v = 0.f;
#pragma unroll
        for (int i = 0; i < 8; ++i) v += part[i][t];
        smean[t] = v * (1.0f / I_);
    }
    __syncthreads();
    if (t < 16) {
        float a = rb1[t];
#pragma unroll
        for (int c2 = 0; c2 < 32; ++c2) a += smean[c2] * rw1[t * 32 + c2];
        h[t] = geluf(a);
    }
    __syncthreads();
    if (t == 0) {
        float lg[3], mx = -1e30f;
        for (int k = 0; k < 3; ++k) {
            float a = rb2[k];
            for (int j = 0; j < 16; ++j) a += h[j] * rw2[k * 16 + j];
            lg[k] = a; mx = fmaxf(mx, a);
        }
        float d = 0.f;
        for (int k = 0; k < 3; ++k) { lg[k] = __expf(lg[k] - mx); d += lg[k]; }
        float inv = 1.f / d;
        for (int k = 0; k < 3; ++k) wp[b * 3 + k] = lg[k] * inv;
    }
}

// ---------------------------------------------------------------- k_phi
__global__ void k_phi(const float* __restrict__ P0, const float* __restrict__ P1,
                      const float* __restrict__ P2, const int* __restrict__ cyc,
                      const float* __restrict__ wp, float* __restrict__ phis) {
    int b = blockIdx.x, t = threadIdx.x;  // 128 threads
    __shared__ float pm[I_];
    float p0 = wp[b * 3 + 0], p1 = wp[b * 3 + 1], p2 = wp[b * 3 + 2];
    int cy = cyc[b];
    for (int l = t; l < I_; l += 128) {
        float acc = 0.f;
        {
            int idx = (cy + l) % 24;
            const float4* r = (const float4*)(P0 + idx * 32);
            float s4 = 0.f;
#pragma unroll
            for (int i = 0; i < 8; ++i) { float4 v = r[i]; s4 += v.x + v.y + v.z + v.w; }
            acc += p0 * s4;
        }
        {
            int idx = (cy + l) % 168;
            const float4* r = (const float4*)(P1 + idx * 32);
            float s4 = 0.f;
#pragma unroll
            for (int i = 0; i < 8; ++i) { float4 v = r[i]; s4 += v.x + v.y + v.z + v.w; }
            acc += p1 * s4;
        }
        {
            int idx = (cy + l) % 336;
            const float4* r = (const float4*)(P2 + idx * 32);
            float s4 = 0.f;
#pragma unroll
            for (int i = 0; i < 8; ++i) { float4 v = r[i]; s4 += v.x + v.y + v.z + v.w; }
            acc += p2 * s4;
        }
        pm[l] = acc * (1.0f / 32.0f);
    }
    __syncthreads();
    if (t < PN_) {
        float sum = 0.f;
#pragma unroll
        for (int j = 0; j < 16; ++j) {
            int l = t * ST_ + j; if (l > 511) l = 511;
            sum += pm[l];
        }
        phis[b * PN_ + t] = sum * (1.0f / 16.0f);
    }
}

// ---------------------------------------------------------------- k_attn
// Single-pass unnormalized softmax; kk-split into NS parts (runtime).
__global__ void __launch_bounds__(256) k_attn(
        const float* __restrict__ s, const int* __restrict__ cyc,
        const float* __restrict__ A0, const float* __restrict__ A1, const float* __restrict__ A2,
        const float* __restrict__ P0, const float* __restrict__ P1, const float* __restrict__ P2,
        float* __restrict__ pd, float* __restrict__ pcs, int NS, int klen) {
    int bx = blockIdx.x;
    int kh = bx % NS, qh = bx / NS;
    int l = qh * 256 + threadIdx.x;
    int k3 = blockIdx.y, b = blockIdx.z;
    const float* Atab; const float* Ptab; int Wk;
    if (k3 == 0)      { Atab = A0; Ptab = P0; Wk = 24;  }
    else if (k3 == 1) { Atab = A1; Ptab = P1; Wk = 168; }
    else              { Atab = A2; Ptab = P2; Wk = 336; }
    int idx = (cyc[b] + l) % Wk;
    float4 qr[8];
    {
        const float4* Ar = (const float4*)(Atab + idx * 32);
        const float4* Pr = (const float4*)(Ptab + idx * 32);
#pragma unroll
        for (int i = 0; i < 8; ++i) {
            float4 a = Ar[i], p = Pr[i];
            float4 q;
            q.x = softplusf(a.x) * __cosf(p.x);
            q.y = softplusf(a.y) * __cosf(p.y);
            q.z = softplusf(a.z) * __cosf(p.z);
            q.w = softplusf(a.w) * __cosf(p.w);
            qr[i] = q;
        }
    }
    const float4* sb = (const float4*)(s + ((size_t)b * I_ + kh * klen) * C_);
    const float rs = 0.17677669529663687f;  // 1/sqrt(32)
    float d = 0.f;
    float4 cs[8];
#pragma unroll
    for (int i = 0; i < 8; ++i) cs[i] = make_float4(0.f, 0.f, 0.f, 0.f);
#pragma unroll 2
    for (int kk = 0; kk < klen; ++kk) {
        const float4* srow = sb + kk * 8;
        float4 sv[8];
        float acc = 0.f;
#pragma unroll
        for (int i = 0; i < 8; ++i) {
            sv[i] = srow[i];
            acc += qr[i].x * sv[i].x + qr[i].y * sv[i].y + qr[i].z * sv[i].z + qr[i].w * sv[i].w;
        }
        float w = __expf(acc * rs);
        d += w;
#pragma unroll
        for (int i = 0; i < 8; ++i) {
            cs[i].x += w * sv[i].x; cs[i].y += w * sv[i].y;
            cs[i].z += w * sv[i].z; cs[i].w += w * sv[i].w;
        }
    }
    int h = k3 * NS + kh;
    pd[((size_t)h * B_ + b) * I_ + l] = d;
    float* outp = pcs + (((size_t)h * B_ + b) * C_) * I_ + l;
#pragma unroll
    for (int i = 0; i < 8; ++i) {
        outp[(size_t)(i * 4 + 0) * I_] = cs[i].x;
        outp[(size_t)(i * 4 + 1) * I_] = cs[i].y;
        outp[(size_t)(i * 4 + 2) * I_] = cs[i].z;
        outp[(size_t)(i * 4 + 3) * I_] = cs[i].w;
    }
}

// ---------------------------------------------------------------- k_combine
// Merge NS softmax parts, add to s, transpose (b,l,c)->(n,l); also transpose t.
__global__ void k_combine(const float* __restrict__ s, const float* __restrict__ t,
                          const float* __restrict__ pd, const float* __restrict__ pcs,
                          const float* __restrict__ wp,
                          float* __restrict__ srow, float* __restrict__ trow, int NS) {
    int b = blockIdx.x, l0 = blockIdx.y * 32;
    int tt_ = threadIdx.x;
    __shared__ float st[32][33], tl[32][33];
    __shared__ float rw[3][32];
#pragma unroll
    for (int r = 0; r < 4; ++r) {
        int lin = r * 256 + tt_;
        int lq = lin >> 5, c = lin & 31;
        st[lq][c] = s[((size_t)b * I_ + l0 + lq) * C_ + c];
        tl[lq][c] = t[((size_t)b * I_ + l0 + lq) * C_ + c];
    }
    if (tt_ < 96) {
        int k3 = tt_ >> 5, lq = tt_ & 31;
        float d = 0.f;
        for (int kh = 0; kh < NS; ++kh)
            d += pd[((size_t)(k3 * NS + kh) * B_ + b) * I_ + l0 + lq];
        rw[k3][lq] = wp[b * 3 + k3] / d;
    }
    __syncthreads();
#pragma unroll
    for (int r = 0; r < 4; ++r) {
        int lin = r * 256 + tt_;
        int co = lin >> 5, lo = lin & 31;
        float sum = 0.f;
        for (int k3 = 0; k3 < 3; ++k3) {
            float v = 0.f;
            for (int kh = 0; kh < NS; ++kh)
                v += pcs[(((size_t)(k3 * NS + kh) * B_ + b) * C_ + co) * I_ + l0 + lo];
            sum += rw[k3][lo] * v;
        }
        size_t oi = ((size_t)(b * C_ + co)) * I_ + l0 + lo;
        srow[oi] = st[lo][co] + sum;
        trow[oi] = tl[lo][co];
    }
}

// ---------------------------------------------------------------- k_patch
// 256 threads: p = patch (0..63), w = worker (0..3)
__global__ void __launch_bounds__(256) k_patch(
        const float* __restrict__ srow, const float* __restrict__ phis,
        const float* __restrict__ Wqkv, const float* __restrict__ bqkv,
        const float* __restrict__ Wo, const float* __restrict__ bo,
        const float* __restrict__ alpha_p, float* __restrict__ sx) {
    int n = blockIdx.x, t = threadIdx.x;
    int p = t & 63, w = t >> 6;
    int b = n >> 5;
    __shared__ float spl[64][17];
    __shared__ float ql[64][17], kl[64][17], vl[64][17];
    __shared__ float blds[64][65];
    __shared__ float phil[64];
    __shared__ float wq[48][16];
    __shared__ float wo[16][16];
    __shared__ float o2l[64][17];
    float alpha = alpha_p[0];
    for (int i = t; i < 768; i += 256) wq[i >> 4][i & 15] = Wqkv[i];
    if (t < 256) wo[t >> 4][t & 15] = Wo[t];
    if (t < 64) phil[t] = phis[b * PN_ + t];
    const float* srn = srow + (size_t)n * I_;
#pragma unroll
    for (int jj = 0; jj < 4; ++jj) {
        int j = w * 4 + jj;
        int l = p * ST_ + j; if (l > 511) l = 511;
        spl[p][j] = srn[l];
    }
    __syncthreads();
    // qkv: worker w computes outputs w*12 .. w*12+11
#pragma unroll
    for (int oo = 0; oo < 12; ++oo) {
        int o = w * 12 + oo;
        float a = bqkv[o];
#pragma unroll
        for (int i2 = 0; i2 < 16; ++i2) a += spl[p][i2] * wq[o][i2];
        if (o < 16) ql[p][o] = a;
        else if (o < 32) kl[p][o - 16] = a;
        else vl[p][o - 32] = a;
    }
    float phit = phil[p];
#pragma unroll
    for (int jj = 0; jj < 16; ++jj) {
        int ss = w * 16 + jj;
        blds[p][ss] = alpha * __cosf(phit - phil[ss]);
    }
    __syncthreads();
    const float rs2 = 0.70710678118654752f;
#pragma unroll
    for (int hh = 0; hh < 2; ++hh) {
        int h = 2 * w + hh;
        float q0 = ql[p][2 * h], q1 = ql[p][2 * h + 1];
        float mh = -1e30f;
        for (int ss = 0; ss < 64; ++ss) {
            float sc = (q0 * kl[ss][2 * h] + q1 * kl[ss][2 * h + 1]) * rs2 + blds[p][ss];
            mh = fmaxf(mh, sc);
        }
        float dh = 0.f, o0 = 0.f, o1 = 0.f;
        for (int ss = 0; ss < 64; ++ss) {
            float sc = (q0 * kl[ss][2 * h] + q1 * kl[ss][2 * h + 1]) * rs2 + blds[p][ss];
            float wgt = __expf(sc - mh);
            dh += wgt; o0 += wgt * vl[ss][2 * h]; o1 += wgt * vl[ss][2 * h + 1];
        }
        float inv = 1.f / dh;
        o2l[p][2 * h] = o0 * inv; o2l[p][2 * h + 1] = o1 * inv;
    }
    __syncthreads();
    float* sxr = sx + ((size_t)n * PN_ + p) * PL_;
#pragma unroll
    for (int ii = 0; ii < 4; ++ii) {
        int i2 = w * 4 + ii;
        float a = bo[i2];
#pragma unroll
        for (int j = 0; j < 16; ++j) a += o2l[p][j] * wo[i2][j];
        sxr[i2] = geluf(spl[p][i2] + a);
    }
}

// ---------------------------------------------------------------- k_bn_stats
__global__ void k_bn_stats(const float* __restrict__ sx, float* __restrict__ bnpart) {
    int pn = blockIdx.x, chunk = blockIdx.y, t = threadIdx.x;
    __shared__ float r1[256], r2[256];
    int j4 = t & 3, nb = t >> 2;
    float s1 = 0.f, s2 = 0.f;
    for (int i = 0; i < 8; ++i) {
        int n = chunk * 512 + nb + i * 64;
        float4 v = *(const float4*)(sx + ((size_t)n * PN_ + pn) * PL_ + j4 * 4);
        s1 += v.x + v.y + v.z + v.w;
        s2 += v.x * v.x + v.y * v.y + v.z * v.z + v.w * v.w;
    }
    r1[t] = s1; r2[t] = s2;
    __syncthreads();
    for (int st = 128; st > 0; st >>= 1) {
        if (t < st) { r1[t] += r1[t + st]; r2[t] += r2[t + st]; }
        __syncthreads();
    }
    if (t == 0) {
        bnpart[(pn * 4 + chunk) * 2 + 0] = r1[0];
        bnpart[(pn * 4 + chunk) * 2 + 1] = r2[0];
    }
}

// ---------------------------------------------------------------- k_bn_apply
__global__ void k_bn_apply(float* __restrict__ sx, const float* __restrict__ bnpart,
                           const float* __restrict__ g, const float* __restrict__ bb) {
    int g4 = blockIdx.x * 256 + threadIdx.x;
    int pn = (g4 >> 2) & 63;
    float s1 = 0.f, s2 = 0.f;
#pragma unroll
    for (int ch = 0; ch < 4; ++ch) {
        s1 += bnpart[(pn * 4 + ch) * 2 + 0];
        s2 += bnpart[(pn * 4 + ch) * 2 + 1];
    }
    const float inv = 1.0f / (N_ * PL_);
    float mu = s1 * inv;
    float var = s2 * inv - mu * mu;
    float rstd = rsqrtf(var + 1e-5f);
    float gg = g[pn], bbv = bb[pn];
    float4* p = (float4*)sx + g4;
    float4 v = *p;
    v.x = (v.x - mu) * rstd * gg + bbv;
    v.y = (v.y - mu) * rstd * gg + bbv;
    v.z = (v.z - mu) * rstd * gg + bbv;
    v.w = (v.w - mu) * rstd * gg + bbv;
    *p = v;
}

// ---------------------------------------------------------------- k_gemm32
template <int ACT>
__global__ void __launch_bounds__(128) k_gemm32(const float* __restrict__ A,
                                                const float* __restrict__ W,
                                                const float* __restrict__ bias,
                                                float* __restrict__ Cout,
                                                int M, int Nn, int K) {
    __shared__ float at[32][36];
    __shared__ float wt[32][36];
    int bm = blockIdx.x * 32, bn = blockIdx.y * 32;
    int t = threadIdx.x;
    int lr = t >> 2, lk = (t & 3) * 8;
    int tm = (t & 15) * 2, tn = (t >> 4) * 4;
    float acc[2][4] = {};
    for (int k0 = 0; k0 < K; k0 += 32) {
        float4 a0 = *(const float4*)(A + (size_t)(bm + lr) * K + k0 + lk);
        float4 a1 = *(const float4*)(A + (size_t)(bm + lr) * K + k0 + lk + 4);
        float4 w0 = *(const float4*)(W + (size_t)(bn + lr) * K + k0 + lk);
        float4 w1 = *(const float4*)(W + (size_t)(bn + lr) * K + k0 + lk + 4);
        __syncthreads();
        at[lk + 0][lr] = a0.x; at[lk + 1][lr] = a0.y; at[lk + 2][lr] = a0.z; at[lk + 3][lr] = a0.w;
        at[lk + 4][lr] = a1.x; at[lk + 5][lr] = a1.y; at[lk + 6][lr] = a1.z; at[lk + 7][lr] = a1.w;
        wt[lk + 0][lr] = w0.x; wt[lk + 1][lr] = w0.y; wt[lk + 2][lr] = w0.z; wt[lk + 3][lr] = w0.w;
        wt[lk + 4][lr] = w1.x; wt[lk + 5][lr] = w1.y; wt[lk + 6][lr] = w1.z; wt[lk + 7][lr] = w1.w;
        __syncthreads();
#pragma unroll
        for (int kk = 0; kk < 32; ++kk) {
            float2 a2 = *(const float2*)&at[kk][tm];
            float4 w4 = *(const float4*)&wt[kk][tn];
            acc[0][0] += a2.x * w4.x; acc[0][1] += a2.x * w4.y;
            acc[0][2] += a2.x * w4.z; acc[0][3] += a2.x * w4.w;
            acc[1][0] += a2.y * w4.x; acc[1][1] += a2.y * w4.y;
            acc[1][2] += a2.y * w4.z; acc[1][3] += a2.y * w4.w;
        }
    }
#pragma unroll
    for (int i = 0; i < 2; ++i) {
#pragma unroll
        for (int j = 0; j < 4; ++j) {
            float v = acc[i][j] + bias[bn + tn + j];
            if (ACT) v = geluf(v);
            Cout[(size_t)(bm + tm + i) * Nn + bn + tn + j] = v;
        }
    }
}

// ---------------------------------------------------------------- k_rowmlp4
__global__ void k_rowmlp4(const float* __restrict__ g3, const float* __restrict__ W4,
                          const float* __restrict__ b4, float* __restrict__ sxf) {
    int n = blockIdx.x, t = threadIdx.x;  // 128 threads
    __shared__ float row[192];
    for (int j = t; j < 192; j += 128) row[j] = g3[(size_t)n * 192 + j];
    __syncthreads();
    if (t < 96) {
        float a = b4[t];
        const float* wr = W4 + t * 192;
#pragma unroll 4
        for (int j = 0; j < 192; ++j) a += row[j] * wr[j];
        sxf[(size_t)n * 96 + t] = a;
    }
}

// ---------------------------------------------------------------- k_u (+ fused low-pass)
__global__ void k_u(const float* __restrict__ u1, const float* __restrict__ ln1g,
                    const float* __restrict__ ln1b, const float* __restrict__ W6,
                    const float* __restrict__ b6, const float* __restrict__ ln2g,
                    const float* __restrict__ ln2b, const float* __restrict__ W7,
                    const float* __restrict__ b7, float* __restrict__ u2out) {
    int n = blockIdx.x, t = threadIdx.x;  // 192 threads
    __shared__ float a[192];
    __shared__ float red1[256], red2[256];
    __shared__ float c2[48];
    __shared__ float stat[2];
    __shared__ float u3l[96];
    __shared__ float cosb[5][96], sinb[5][96];
    __shared__ float coef[9];
    if (t < 96) {
#pragma unroll
        for (int k = 0; k < 5; ++k) {
            float sv, cv2;
            __sincosf(6.283185307179586f * (float)(k * t) / 96.0f, &sv, &cv2);
            cosb[k][t] = cv2; sinb[k][t] = sv;
        }
    }
    const float* ur = u1 + (size_t)n * 384;
    float av = 0.5f * (ur[2 * t] + ur[2 * t + 1]);
    red1[t] = av; red2[t] = av * av;
    if (t < 64) { red1[192 + t] = 0.f; red2[192 + t] = 0.f; }
    __syncthreads();
    for (int st = 128; st > 0; st >>= 1) {
        if (t < st) { red1[t] += red1[t + st]; red2[t] += red2[t + st]; }
        __syncthreads();
    }
    if (t == 0) {
        float mu = red1[0] * (1.0f / 192.0f);
        float var = red2[0] * (1.0f / 192.0f) - mu * mu;
        stat[0] = mu; stat[1] = rsqrtf(var + 1e-5f);
    }
    __syncthreads();
    a[t] = (av - stat[0]) * stat[1] * ln1g[t] + ln1b[t];
    __syncthreads();
    float bv = 0.f;
    if (t < 96) {
        bv = b6[t];
        const float* wr = W6 + t * 192;
#pragma unroll 4
        for (int j = 0; j < 192; ++j) bv += a[j] * wr[j];
    }
    __syncthreads();
    if (t < 96) red1[t] = bv;
    __syncthreads();
    float cv = 0.f;
    if (t < 48) cv = 0.5f * (red1[2 * t] + red1[2 * t + 1]);
    __syncthreads();
    if (t < 48) { red1[t] = cv; red2[t] = cv * cv; }
    else if (t < 64) { red1[t] = 0.f; red2[t] = 0.f; }
    __syncthreads();
    for (int st = 32; st > 0; st >>= 1) {
        if (t < st) { red1[t] += red1[t + st]; red2[t] += red2[t + st]; }
        __syncthreads();
    }
    if (t == 0) {
        float mu = red1[0] * (1.0f / 48.0f);
        float var = red2[0] * (1.0f / 48.0f) - mu * mu;
        stat[0] = mu; stat[1] = rsqrtf(var + 1e-5f);
    }
    __syncthreads();
    if (t < 48) c2[t] = (cv - stat[0]) * stat[1] * ln2g[t] + ln2b[t];
    __syncthreads();
    if (t < 96) {
        float acc = b7[t];
        const float* wr = W7 + t * 48;
#pragma unroll
        for (int j = 0; j < 48; ++j) acc += c2[j] * wr[j];
        u3l[t] = acc;
    }
    __syncthreads();
    // low-pass: project onto first-5 rfft bins (9 real coeffs), add back
    if (t < 9) {
        int k = (t < 5) ? t : t - 4;
        const float* bas = (t < 5) ? cosb[k] : sinb[k];
        float acc = 0.f;
#pragma unroll 4
        for (int m = 0; m < 96; ++m) acc += u3l[m] * bas[m];
        coef[t] = acc;
    }
    __syncthreads();
    if (t < 96) {
        float rec = coef[0];
#pragma unroll
        for (int k = 1; k <= 4; ++k)
            rec += 2.0f * (coef[k] * cosb[k][t] + coef[4 + k] * sinb[k][t]);
        u2out[(size_t)n * 96 + t] = u3l[t] + rec * (1.0f / 96.0f);
    }
}

// ---------------------------------------------------------------- k_conv
__global__ void k_conv(const float* __restrict__ u2, const float* __restrict__ tw,
                       const float* __restrict__ tb, float* __restrict__ u4) {
    int b = blockIdx.x, xq = blockIdx.y, t = threadIdx.x;
    int x0 = xq * 24;
    __shared__ float ub[32][26];
    __shared__ float twl[3072];
    for (int i = t; i < 832; i += 256) {
        int ic = i / 26, xx = i % 26;
        int gx = x0 + xx - 1;
        ub[ic][xx] = (gx >= 0 && gx < 96) ? u2[((size_t)b * 32 + ic) * 96 + gx] : 0.f;
    }
    for (int i = t; i < 3072; i += 256) twl[i] = tw[i];
    __syncthreads();
    for (int i = t; i < 768; i += 256) {
        int oc = i / 24, xx = i % 24;
        float acc = tb[oc];
#pragma unroll 8
        for (int ic = 0; ic < 32; ++ic) {
            const float* wv = twl + (oc * 32 + ic) * 3;
            acc += ub[ic][xx] * wv[0] + ub[ic][xx + 1] * wv[1] + ub[ic][xx + 2] * wv[2];
        }
        u4[((size_t)b * 32 + oc) * 96 + x0 + xx] = ub[oc][xx + 1] + geluf(acc);
    }
}

// ---------------------------------------------------------------- k_out
__global__ void k_out(const float* __restrict__ sxf, const float* __restrict__ u4,
                      const float* __restrict__ W8, const float* __restrict__ b8,
                      float* __restrict__ out) {
    int b = blockIdx.x, oq = blockIdx.y, t = threadIdx.x;
    __shared__ float ld[32][193];
    for (int i = t; i < 32 * 96; i += 256) {
        int c = i / 96, j = i % 96;
        ld[c][j]      = sxf[((size_t)(b * 32 + c)) * 96 + j];
        ld[c][96 + j] = u4[((size_t)(b * 32 + c)) * 96 + j];
    }
    __syncthreads();
    for (int i = t; i < 24 * 32; i += 256) {
        int o = oq * 24 + (i >> 5), c = i & 31;
        float acc = b8[o];
        const float* wr = W8 + o * 192;
#pragma unroll 4
        for (int j = 0; j < 192; ++j) acc += ld[c][j] * wr[j];
        out[((size_t)b * 96 + o) * 32 + c] = acc;
    }
}

// ---------------------------------------------------------------- launch
extern "C" void kernel_launch(void* const* d_in, const int* in_sizes, int n_in,
                              void* d_out, int out_size, void* d_ws, size_t ws_size,
                              hipStream_t stream) {
    const float* s    = (const float*)d_in[0];
    const float* t    = (const float*)d_in[1];
    const int*   cyc  = (const int*)d_in[2];
    const float* rw1  = (const float*)d_in[3];
    const float* rb1  = (const float*)d_in[4];
    const float* rw2  = (const float*)d_in[5];
    const float* rb2  = (const float*)d_in[6];
    const float* A0   = (const float*)d_in[7];
    const float* A1   = (const float*)d_in[8];
    const float* A2   = (const float*)d_in[9];
    const float* P0   = (const float*)d_in[10];
    const float* P1   = (const float*)d_in[11];
    const float* P2   = (const float*)d_in[12];
    const float* Wqkv = (const float*)d_in[13];
    const float* bqkv = (const float*)d_in[14];
    const float* Wo   = (const float*)d_in[15];
    const float* bo   = (const float*)d_in[16];
    const float* alpha= (const float*)d_in[17];
    const float* bn_g = (const float*)d_in[18];
    const float* bn_b = (const float*)d_in[19];
    const float* W3   = (const float*)d_in[20];
    const float* b3   = (const float*)d_in[21];
    const float* W4   = (const float*)d_in[22];
    const float* b4   = (const float*)d_in[23];
    const float* W5   = (const float*)d_in[24];
    const float* b5   = (const float*)d_in[25];
    const float* W6   = (const float*)d_in[26];
    const float* b6   = (const float*)d_in[27];
    const float* W7   = (const float*)d_in[28];
    const float* b7   = (const float*)d_in[29];
    const float* W8   = (const float*)d_in[30];
    const float* b8   = (const float*)d_in[31];
    const float* ln1g = (const float*)d_in[32];
    const float* ln1b = (const float*)d_in[33];
    const float* ln2g = (const float*)d_in[34];
    const float* ln2b = (const float*)d_in[35];
    const float* tew  = (const float*)d_in[36];
    const float* teb  = (const float*)d_in[37];

    // choose kk-split based on workspace size (behavior identical every call)
    const size_t need4 = (size_t)(4864 + 2097152 + 4 * (98304 + 3145728)) * 4;
    int NS = (ws_size >= need4) ? 4 : 2;
    int klen = I_ / NS;

    float* ws     = (float*)d_ws;
    float* wp     = ws;                         // 192
    float* phis   = ws + 192;                   // 4096
    float* bnpart = ws + 4288;                  // 512
    float* srow   = ws + 4864;                  // 1048576
    float* trow   = srow + 1048576;             // 1048576
    float* R      = trow + 1048576;             // overlay region
    // phase 1 overlay
    float* pd  = R;                             // 98304*NS
    float* pcs = R + (size_t)98304 * NS;        // 3145728*NS
    // phase 2 overlay
    float* sx  = R;                             // 2097152
    float* g3  = R + 2097152;                   // 393216
    float* sxf = R + 2490368;                   // 196608
    float* u1  = R + 2686976;                   // 786432
    float* u2f = R + 3473408;                   // 196608
    float* u4f = R + 3670016;                   // 196608
    float* out = (float*)d_out;

    k_head<<<64, 256, 0, stream>>>(s, rw1, rb1, rw2, rb2, wp);
    k_phi<<<64, 128, 0, stream>>>(P0, P1, P2, cyc, wp, phis);
    k_attn<<<dim3(2 * NS, 3, 64), 256, 0, stream>>>(s, cyc, A0, A1, A2, P0, P1, P2, pd, pcs, NS, klen);
    k_combine<<<dim3(64, 16), 256, 0, stream>>>(s, t, pd, pcs, wp, srow, trow, NS);
    k_patch<<<2048, 256, 0, stream>>>(srow, phis, Wqkv, bqkv, Wo, bo, alpha, sx);
    k_bn_stats<<<dim3(64, 4), 256, 0, stream>>>(sx, bnpart);
    k_bn_apply<<<2048, 256, 0, stream>>>(sx, bnpart, bn_g, bn_b);
    k_gemm32<1><<<dim3(64, 6), 128, 0, stream>>>(sx, W3, b3, g3, 2048, 192, 1024);
    k_rowmlp4<<<2048, 128, 0, stream>>>(g3, W4, b4, sxf);
    k_gemm32<0><<<dim3(64, 12), 128, 0, stream>>>(trow, W5, b5, u1, 2048, 384, 512);
    k_u<<<2048, 192, 0, stream>>>(u1, ln1g, ln1b, W6, b6, ln2g, ln2b, W7, b7, u2f);
    k_conv<<<dim3(64, 4), 256, 0, stream>>>(u2f, tew, teb, u4f);
    k_out<<<dim3(64, 4), 256, 0, stream>>>(sxf, u4f, W8, b8, out);
}